// Round 1
// 285.476 us; speedup vs baseline: 1.0889x; 1.0889x over previous
//
#include <hip/hip_runtime.h>
#include <stdint.h>

// Problem constants (B=4, N=4096, D_MODEL=1024, H=16, Dh=64, K_EIG=16)
#define NTOK   16384          // B*N tokens
#define DM     1024           // d_model (GEMM K)
#define NQKV   3072           // folded output features: [Qf|Kf|Vf], each 16*64

typedef __attribute__((ext_vector_type(8))) _Float16 half8;
typedef __attribute__((ext_vector_type(4))) _Float16 half4;
typedef __attribute__((ext_vector_type(4))) float    float4v;

#define MFMA16 __builtin_amdgcn_mfma_f32_16x16x32_f16
#define BARX()  do{ asm volatile("" ::: "memory"); __builtin_amdgcn_s_barrier(); asm volatile("" ::: "memory"); }while(0)
#define LGKM0() asm volatile("s_waitcnt lgkmcnt(0)" ::: "memory")
#define VMCNT(N) asm volatile("s_waitcnt vmcnt(" #N ")" ::: "memory")

__device__ __forceinline__ void async_cp16(const void* g, void* l){
  __builtin_amdgcn_global_load_lds(
      (const __attribute__((address_space(1))) void*)g,
      (__attribute__((address_space(3))) void*)l, 16, 0, 0);
}

// ---------------- x fp32 -> fp16 (16-B stores) ----------------
__global__ void cvt_x_kernel(const float* __restrict__ x, _Float16* __restrict__ xb){
  int i = (blockIdx.x * blockDim.x + threadIdx.x) * 8;
  const int stride = gridDim.x * blockDim.x * 8;
  for(; i < NTOK * DM; i += stride){
    float4v v0 = *(const float4v*)(x + i);
    float4v v1 = *(const float4v*)(x + i + 4);
    half8 o;
    o[0]=(_Float16)v0[0]; o[1]=(_Float16)v0[1]; o[2]=(_Float16)v0[2]; o[3]=(_Float16)v0[3];
    o[4]=(_Float16)v1[0]; o[5]=(_Float16)v1[1]; o[6]=(_Float16)v1[2]; o[7]=(_Float16)v1[3];
    *(half8*)(xb + i) = o;
  }
}

// ---------------- fold E,w into weights; WT[n][c] fp16, W read ONCE ----------------
__global__ __launch_bounds__(256)
void prep_w_kernel(const float* __restrict__ Wq, const float* __restrict__ Wk,
                   const float* __restrict__ Wv, const float* __restrict__ E,
                   const float* __restrict__ fw, _Float16* __restrict__ WT){
  __shared__ float Wl[8][1032];            // padded rows
  __shared__ float oT[16][8][65];          // [kE][c][d], pad 65 -> conflict-free
  __shared__ float sEv[256];
  __shared__ float sFw[16];
  const int t  = threadIdx.x;
  const int bx = blockIdx.x;               // 0..383
  const int p  = bx >> 7, rt = bx & 127;   // p in 0..2, rt in 0..127
  const int c0 = rt * 8;
  const float* W = (p == 0) ? Wq : (p == 1) ? Wk : Wv;
  sEv[t] = E[t];
  if(t < 16) sFw[t] = fw[t];

  #pragma unroll
  for(int j = 0; j < 32; ++j){
    const int flat = j * 256 + t;          // 0..8191
    const int row = flat >> 10, col = flat & 1023;
    Wl[row][col] = W[(size_t)(c0 + row) * 1024 + col];
  }
  __syncthreads();

  const int d = t & 63, rg = t >> 6;
  #pragma unroll
  for(int rr = 0; rr < 2; ++rr){
    const int row = rg * 2 + rr;
    float w[16];
    #pragma unroll
    for(int h = 0; h < 16; ++h) w[h] = Wl[row][h * 64 + d];
    #pragma unroll
    for(int ke = 0; ke < 16; ++ke){
      float acc = 0.f;
      #pragma unroll
      for(int h = 0; h < 16; ++h) acc += sEv[h * 16 + ke] * w[h];
      oT[ke][row][d] = acc * sFw[ke];
    }
  }
  __syncthreads();

  #pragma unroll
  for(int k4 = 0; k4 < 4; ++k4){
    const int idx = k4 * 256 + t;          // 0..1023
    const int ke = idx >> 6, dd = idx & 63;
    half8 o;
    #pragma unroll
    for(int c = 0; c < 8; ++c) o[c] = (_Float16)oT[ke][c][dd];
    const int n = (p * 16 + ke) * 64 + dd;
    *(half8*)(WT + (size_t)n * 1024 + c0) = o;
  }
}

// ---------------- folded bias fb[n] (fp32) ----------------
__global__ void prep_b_kernel(const float* __restrict__ bq, const float* __restrict__ bk,
                              const float* __restrict__ bv, const float* __restrict__ E,
                              const float* __restrict__ fw, float* __restrict__ fb){
  const int n = blockIdx.x * blockDim.x + threadIdx.x;
  if(n >= NQKV) return;
  const int p = n >> 10, kE = (n >> 6) & 15, d = n & 63;
  const float* b = (p == 0) ? bq : (p == 1) ? bk : bv;
  float acc = 0.f;
  for(int h = 0; h < 16; ++h) acc += E[h * 16 + kE] * b[h * 64 + d];
  fb[n] = acc * fw[kE];
}

// ---------------- 256x256 8-phase counted-vmcnt GEMM (T1+T2+T3+T4+T5) ----------------
// 512 thr = 8 waves (2M x 4N), BK=64, dbuf at K-tile granularity (2 x 64KB LDS).
// STRIDED wave tiling: wave wr owns row-groups {wr + 2m}, wave wc col-groups {wc + 4n},
// so quadrant (mh,nh) reads exactly A-half mh / B-half nh -> staggered first-reads:
//   p1=(0,0): Ah0,Bh0   p2=(0,1): +Bh1   p3=(1,0): +Ah1   p4=(1,1): (regs only)
// Stage stream per K-tile T (into buf[(T+1)&1], NEVER the buffer being read):
//   p1: T+1.Ah0   p2: T+1.Bh0   p3: T+1.Bh1   p4: T+1.Ah1
// vmcnt(4) at p1/p2/p4 -> every half-tile has >=3 phases of flight; loop never drains to 0.
// LDS swizzle (both-sides XOR, rule #21): 16B chunk col ^= (row&7); gload_lds dest linear,
// global SOURCE pre-permuted (stC), ds_read address XOR'd (qsw) -> stride-128B reads 2-way.
struct FlagF { static constexpr bool value = false; };
struct FlagT { static constexpr bool value = true; };

__global__ __launch_bounds__(512, 2)
void gemm_qkv_kernel(const _Float16* __restrict__ A,   // [16384][1024] fp16
                     const _Float16* __restrict__ BT,  // [3072][1024] fp16
                     const float* __restrict__ bias,   // [3072] fp32
                     _Float16* __restrict__ C){        // [16384][3072] fp16
  extern __shared__ _Float16 lds[];   // 65536 halfs = 128KB: buf[2] x {A 16384, B 16384}
  const int t = threadIdx.x;
  const int lane = t & 63, wv = t >> 6;
  const int l15 = lane & 15, q = lane >> 4;
  const int wr = wv >> 2, wc = wv & 3;           // 2M x 4N waves

  // T1: XCD band swizzle. 768 wgs, 96/XCD = 8 m-tiles x 12 n-tiles, m fast (B-tile L2-hot).
  const int bid = blockIdx.x;
  const int xcd = bid & 7, s = bid >> 3;         // s in 0..95
  const int mt = xcd * 8 + (s & 7);              // 0..63
  const int nt = s >> 3;                         // 0..11
  const int m0 = mt * 256, n0 = nt * 256;

  // staging lane constants (source pre-swizzle; dest linear)
  const int stR = wv * 16 + (lane >> 3);                 // row in half-tile (issue1: +8)
  const int stC = (((lane & 7) ^ (lane >> 3)) * 8);      // swizzled col (halfs)
  const int stD = (wv * 128 + lane) * 8;                 // dest (halfs, linear)
  // read-side swizzle: chunk col (halfs) = (kk*32 | q*8) ^ ((l15&7)*8)
  const int qsw = (q * 8) ^ ((l15 & 7) * 8);
  const int aoffb = (wr * 16 + l15) * 64;                // + m*2048 + (qsw ^ kk*32)
  const int boffb = (wc * 16 + l15) * 64;                // + n*4096 + (qsw ^ kk*32)

  auto stgA = [&](_Float16* nb, int kc, int h){
    const _Float16* g = A + (size_t)(m0 + h * 128 + stR) * 1024 + kc + stC;
    _Float16* d = nb + h * 8192 + stD;
    async_cp16(g, d);
    async_cp16(g + 8 * 1024, d + 512);
  };
  auto stgB = [&](_Float16* nb, int kc, int h){
    const _Float16* g = BT + (size_t)(n0 + h * 128 + stR) * 1024 + kc + stC;
    _Float16* d = nb + 16384 + h * 8192 + stD;
    async_cp16(g, d);
    async_cp16(g + 8 * 1024, d + 512);
  };

  float4v acc[8][4];
  #pragma unroll
  for(int m = 0; m < 8; ++m)
    #pragma unroll
    for(int n = 0; n < 4; ++n){ acc[m][n][0]=0.f; acc[m][n][1]=0.f; acc[m][n][2]=0.f; acc[m][n][3]=0.f; }

  half8 aL[4][2], aH[4][2], b0[2][2], b1[2][2];

  // prologue: K0 in stream order [Ah0, Bh0, Bh1, Ah1]; vmcnt(4) -> Ah0,Bh0 landed
  stgA(lds, 0, 0);
  stgB(lds, 0, 0);
  stgB(lds, 0, 1);
  stgA(lds, 0, 1);
  VMCNT(4);
  BARX();

  int kt = 0;
  auto ktile = [&](auto lastc){
    constexpr bool LAST = decltype(lastc)::value;
    const _Float16* pA = lds + (kt & 1) * 32768;
    const _Float16* pB = pA + 16384;
    _Float16* nxt = lds + ((kt + 1) & 1) * 32768;
    const int kn = (kt + 1) * 64;

    // ---- phase 1: quadrant (0,0) ----
    #pragma unroll
    for(int m = 0; m < 4; ++m){
      aL[m][0] = *(const half8*)(pA + aoffb + m * 2048 + qsw);
      aL[m][1] = *(const half8*)(pA + aoffb + m * 2048 + (qsw ^ 32));
    }
    #pragma unroll
    for(int n = 0; n < 2; ++n){
      b0[n][0] = *(const half8*)(pB + boffb + n * 4096 + qsw);
      b0[n][1] = *(const half8*)(pB + boffb + n * 4096 + (qsw ^ 32));
    }
    if constexpr(!LAST) stgA(nxt, kn, 0);
    BARX(); LGKM0();
    __builtin_amdgcn_s_setprio(1);
    #pragma unroll
    for(int m = 0; m < 4; ++m)
      #pragma unroll
      for(int n = 0; n < 2; ++n){
        acc[m][n] = MFMA16(aL[m][0], b0[n][0], acc[m][n], 0, 0, 0);
        acc[m][n] = MFMA16(aL[m][1], b0[n][1], acc[m][n], 0, 0, 0);
      }
    __builtin_amdgcn_s_setprio(0);
    if constexpr(!LAST){ VMCNT(4); } else { VMCNT(2); }   // Bh1 landed (first read p2)
    BARX();

    // ---- phase 2: quadrant (0,1) ----
    #pragma unroll
    for(int n = 0; n < 2; ++n){
      b1[n][0] = *(const half8*)(pB + boffb + (n + 2) * 4096 + qsw);
      b1[n][1] = *(const half8*)(pB + boffb + (n + 2) * 4096 + (qsw ^ 32));
    }
    if constexpr(!LAST) stgB(nxt, kn, 0);
    BARX(); LGKM0();
    __builtin_amdgcn_s_setprio(1);
    #pragma unroll
    for(int m = 0; m < 4; ++m)
      #pragma unroll
      for(int n = 0; n < 2; ++n){
        acc[m][n + 2] = MFMA16(aL[m][0], b1[n][0], acc[m][n + 2], 0, 0, 0);
        acc[m][n + 2] = MFMA16(aL[m][1], b1[n][1], acc[m][n + 2], 0, 0, 0);
      }
    __builtin_amdgcn_s_setprio(0);
    if constexpr(!LAST){ VMCNT(4); } else { VMCNT(0); }   // Ah1 landed (first read p3)
    BARX();

    // ---- phase 3: quadrant (1,0) ----
    #pragma unroll
    for(int m = 0; m < 4; ++m){
      aH[m][0] = *(const half8*)(pA + aoffb + (m + 4) * 2048 + qsw);
      aH[m][1] = *(const half8*)(pA + aoffb + (m + 4) * 2048 + (qsw ^ 32));
    }
    if constexpr(!LAST) stgB(nxt, kn, 1);
    BARX(); LGKM0();
    __builtin_amdgcn_s_setprio(1);
    #pragma unroll
    for(int m = 0; m < 4; ++m)
      #pragma unroll
      for(int n = 0; n < 2; ++n){
        acc[m + 4][n] = MFMA16(aH[m][0], b0[n][0], acc[m + 4][n], 0, 0, 0);
        acc[m + 4][n] = MFMA16(aH[m][1], b0[n][1], acc[m + 4][n], 0, 0, 0);
      }
    __builtin_amdgcn_s_setprio(0);
    BARX();

    // ---- phase 4: quadrant (1,1), regs only ----
    if constexpr(!LAST) stgA(nxt, kn, 1);
    BARX(); LGKM0();
    __builtin_amdgcn_s_setprio(1);
    #pragma unroll
    for(int m = 0; m < 4; ++m)
      #pragma unroll
      for(int n = 0; n < 2; ++n){
        acc[m + 4][n + 2] = MFMA16(aH[m][0], b1[n][0], acc[m + 4][n + 2], 0, 0, 0);
        acc[m + 4][n + 2] = MFMA16(aH[m][1], b1[n][1], acc[m + 4][n + 2], 0, 0, 0);
      }
    __builtin_amdgcn_s_setprio(0);
    if constexpr(!LAST){ VMCNT(4); }                      // next Ah0,Bh0 landed
    BARX();
  };

  for(kt = 0; kt < 15; ++kt) ktile(FlagF{});
  ktile(FlagT{});

  // epilogue: bias + fp16 store (same mapping as verified m97 kernel)
  #pragma unroll
  for(int n = 0; n < 4; ++n){
    const int col = n0 + (n * 4 + wc) * 16 + l15;
    const float bs = bias[col];
    #pragma unroll
    for(int m = 0; m < 8; ++m){
      const int rbase = m0 + (m * 2 + wr) * 16 + q * 4;
      #pragma unroll
      for(int r = 0; r < 4; ++r)
        C[(size_t)(rbase + r) * NQKV + col] = (_Float16)(acc[m][n][r] + bs);
    }
  }
}

// ---------------- per-token spectral attention v3 (unchanged) ----------------
__global__ __launch_bounds__(256)
void attn_kernel(const _Float16* __restrict__ QKV,   // [NTOK][3072] fp16
                 const float* __restrict__ E,        // [16][16] fp32
                 float* __restrict__ out){           // [NTOK][1024] fp32
  __shared__ _Float16 sV[4 * 1024];
  __shared__ _Float16 sE[16 * 32];
  __shared__ _Float16 pT[4][16 * 32];
  __shared__ _Float16 gT[4][16 * 32];

  const int t = threadIdx.x, lane = t & 63, wv = t >> 6;
  const int l15 = lane & 15, q = lane >> 4;

  {
    #pragma unroll
    for(int s = 0; s < 2; ++s){
      const int idx = s * 256 + t;
      const int row = idx >> 5, col = idx & 31;
      sE[idx] = (col < 16) ? (_Float16)E[row * 16 + col] : (_Float16)0.f;
    }
    #pragma unroll
    for(int s = 0; s < 4; ++s){
      const int idx = s * 256 + t;
      const int w = idx >> 8, rem = idx & 255;
      const int off = (rem >> 4) * 32 + 16 + (rem & 15);
      pT[w][off] = (_Float16)0.f;
      gT[w][off] = (_Float16)0.f;
    }
  }

  const _Float16* gb = QKV + (size_t)blockIdx.x * (4 * 3072);
  #pragma unroll
  for(int i = 0; i < 2; ++i){
    const int f = i * 256 + t;
    async_cp16(gb + (f >> 7) * 3072 + 2048 + (f & 127) * 8, sV + f * 8);
  }

  const int tok = blockIdx.x * 4 + wv;
  const _Float16* tg = QKV + (size_t)tok * 3072;

  half8 aK0 = *(const half8*)(tg + 1024 + l15 * 64 + q * 8);
  half8 aK1 = *(const half8*)(tg + 1024 + l15 * 64 + 32 + q * 8);
  half8 bQ0 = *(const half8*)(tg + l15 * 64 + q * 8);
  half8 bQ1 = *(const half8*)(tg + l15 * 64 + 32 + q * 8);
  float4v S; S[0]=0.f; S[1]=0.f; S[2]=0.f; S[3]=0.f;
  S = __builtin_amdgcn_mfma_f32_16x16x32_f16(aK0, bQ0, S, 0, 0, 0);
  S = __builtin_amdgcn_mfma_f32_16x16x32_f16(aK1, bQ1, S, 0, 0, 0);

  float v[4];
  #pragma unroll
  for(int r = 0; r < 4; ++r) v[r] = S[r] * 0.125f;
  float mx = fmaxf(fmaxf(v[0], v[1]), fmaxf(v[2], v[3]));
  mx = fmaxf(mx, __shfl_xor(mx, 16));
  mx = fmaxf(mx, __shfl_xor(mx, 32));
  float e[4];
  #pragma unroll
  for(int r = 0; r < 4; ++r) e[r] = __expf(v[r] - mx);
  float sm = (e[0] + e[1]) + (e[2] + e[3]);
  sm += __shfl_xor(sm, 16);
  sm += __shfl_xor(sm, 32);
  const float rs = 1.f / sm;

  __syncthreads();

  _Float16* pw = pT[wv];
  #pragma unroll
  for(int r = 0; r < 4; ++r) pw[(q * 4 + r) * 32 + l15] = (_Float16)(e[r] * rs);
  half8 bP = *(const half8*)(pw + l15 * 32 + q * 8);
  half8 aE = *(const half8*)(sE + l15 * 32 + q * 8);

  float4v G; G[0]=0.f; G[1]=0.f; G[2]=0.f; G[3]=0.f;
  G = __builtin_amdgcn_mfma_f32_16x16x32_f16(aE, bP, G, 0, 0, 0);

  _Float16* gw = gT[wv];
  #pragma unroll
  for(int r = 0; r < 4; ++r) gw[(q * 4 + r) * 32 + l15] = (_Float16)G[r];
  half8 aG = *(const half8*)(gw + l15 * 32 + q * 8);

  const _Float16* vb = sV + wv * 1024 + (q & 1) * 8 * 64;
  float* ob = out + (size_t)tok * 1024;
  #pragma unroll
  for(int tt = 0; tt < 4; ++tt){
    half8 vf;
    #pragma unroll
    for(int jj = 0; jj < 8; ++jj) vf[jj] = vb[jj * 64 + tt * 16 + l15];
    float4v O; O[0]=0.f; O[1]=0.f; O[2]=0.f; O[3]=0.f;
    O = __builtin_amdgcn_mfma_f32_16x16x32_f16(aG, vf, O, 0, 0, 0);
    #pragma unroll
    for(int r = 0; r < 4; ++r)
      ob[(q * 4 + r) * 64 + tt * 16 + l15] = O[r];
  }
}

extern "C" void kernel_launch(void* const* d_in, const int* in_sizes, int n_in,
                              void* d_out, int out_size, void* d_ws, size_t ws_size,
                              hipStream_t stream){
  const float* x  = (const float*)d_in[0];
  const float* Wq = (const float*)d_in[1];
  const float* bq = (const float*)d_in[2];
  const float* Wk = (const float*)d_in[3];
  const float* bk = (const float*)d_in[4];
  const float* Wv = (const float*)d_in[5];
  const float* bv = (const float*)d_in[6];
  const float* E  = (const float*)d_in[7];
  const float* fw = (const float*)d_in[8];
  float* out = (float*)d_out;

  // workspace layout (needs 136 MB)
  char* ws = (char*)d_ws;
  _Float16* xb  = (_Float16*)ws;                                  // 32 MB
  _Float16* WT  = (_Float16*)(ws + (size_t)32 * 1024 * 1024);     //  6 MB
  float*    fb  = (float*)   (ws + (size_t)39 * 1024 * 1024);     // 12 KB
  _Float16* QKV = (_Float16*)(ws + (size_t)40 * 1024 * 1024);     // 96 MB

  static bool attr_done = false;
  if(!attr_done){
    hipFuncSetAttribute((const void*)gemm_qkv_kernel,
                        hipFuncAttributeMaxDynamicSharedMemorySize, 131072);
    attr_done = true;
  }

  hipLaunchKernelGGL(cvt_x_kernel, dim3(2048), dim3(256), 0, stream, x, xb);
  hipLaunchKernelGGL(prep_w_kernel, dim3(384), dim3(256), 0, stream, Wq, Wk, Wv, E, fw, WT);
  hipLaunchKernelGGL(prep_b_kernel, dim3(12), dim3(256), 0, stream, bq, bk, bv, E, fw, fb);
  hipLaunchKernelGGL(gemm_qkv_kernel, dim3(768), dim3(512), 131072, stream, xb, WT, fb, QKV);
  hipLaunchKernelGGL(attn_kernel, dim3(NTOK / 4), dim3(256), 0, stream, QKV, E, out);
}

// Round 2
// 276.761 us; speedup vs baseline: 1.1232x; 1.0315x over previous
//
#include <hip/hip_runtime.h>
#include <stdint.h>

// Problem constants (B=4, N=4096, D_MODEL=1024, H=16, Dh=64, K_EIG=16)
#define NTOK   16384          // B*N tokens
#define DM     1024           // d_model (GEMM K)
#define NQKV   3072           // folded output features: [Qf|Kf|Vf], each 16*64

typedef __attribute__((ext_vector_type(8))) _Float16 half8;
typedef __attribute__((ext_vector_type(4))) _Float16 half4;
typedef __attribute__((ext_vector_type(4))) float    float4v;

#define MFMA16 __builtin_amdgcn_mfma_f32_16x16x32_f16
#define BARX()  do{ asm volatile("" ::: "memory"); __builtin_amdgcn_s_barrier(); asm volatile("" ::: "memory"); }while(0)
#define VMCNT(N) asm volatile("s_waitcnt vmcnt(" #N ")" ::: "memory")

__device__ __forceinline__ void async_cp16(const void* g, void* l){
  __builtin_amdgcn_global_load_lds(
      (const __attribute__((address_space(1))) void*)g,
      (__attribute__((address_space(3))) void*)l, 16, 0, 0);
}

// ---------------- x fp32 -> fp16 (16-B stores) ----------------
__global__ void cvt_x_kernel(const float* __restrict__ x, _Float16* __restrict__ xb){
  int i = (blockIdx.x * blockDim.x + threadIdx.x) * 8;
  const int stride = gridDim.x * blockDim.x * 8;
  for(; i < NTOK * DM; i += stride){
    float4v v0 = *(const float4v*)(x + i);
    float4v v1 = *(const float4v*)(x + i + 4);
    half8 o;
    o[0]=(_Float16)v0[0]; o[1]=(_Float16)v0[1]; o[2]=(_Float16)v0[2]; o[3]=(_Float16)v0[3];
    o[4]=(_Float16)v1[0]; o[5]=(_Float16)v1[1]; o[6]=(_Float16)v1[2]; o[7]=(_Float16)v1[3];
    *(half8*)(xb + i) = o;
  }
}

// ---------------- fold E,w into weights; WT[n][c] fp16, W read ONCE ----------------
__global__ __launch_bounds__(256)
void prep_w_kernel(const float* __restrict__ Wq, const float* __restrict__ Wk,
                   const float* __restrict__ Wv, const float* __restrict__ E,
                   const float* __restrict__ fw, _Float16* __restrict__ WT){
  __shared__ float Wl[8][1032];            // padded rows
  __shared__ float oT[16][8][65];          // [kE][c][d], pad 65 -> conflict-free
  __shared__ float sEv[256];
  __shared__ float sFw[16];
  const int t  = threadIdx.x;
  const int bx = blockIdx.x;               // 0..383
  const int p  = bx >> 7, rt = bx & 127;   // p in 0..2, rt in 0..127
  const int c0 = rt * 8;
  const float* W = (p == 0) ? Wq : (p == 1) ? Wk : Wv;
  sEv[t] = E[t];
  if(t < 16) sFw[t] = fw[t];

  #pragma unroll
  for(int j = 0; j < 32; ++j){
    const int flat = j * 256 + t;          // 0..8191
    const int row = flat >> 10, col = flat & 1023;
    Wl[row][col] = W[(size_t)(c0 + row) * 1024 + col];
  }
  __syncthreads();

  const int d = t & 63, rg = t >> 6;
  #pragma unroll
  for(int rr = 0; rr < 2; ++rr){
    const int row = rg * 2 + rr;
    float w[16];
    #pragma unroll
    for(int h = 0; h < 16; ++h) w[h] = Wl[row][h * 64 + d];
    #pragma unroll
    for(int ke = 0; ke < 16; ++ke){
      float acc = 0.f;
      #pragma unroll
      for(int h = 0; h < 16; ++h) acc += sEv[h * 16 + ke] * w[h];
      oT[ke][row][d] = acc * sFw[ke];
    }
  }
  __syncthreads();

  #pragma unroll
  for(int k4 = 0; k4 < 4; ++k4){
    const int idx = k4 * 256 + t;          // 0..1023
    const int ke = idx >> 6, dd = idx & 63;
    half8 o;
    #pragma unroll
    for(int c = 0; c < 8; ++c) o[c] = (_Float16)oT[ke][c][dd];
    const int n = (p * 16 + ke) * 64 + dd;
    *(half8*)(WT + (size_t)n * 1024 + c0) = o;
  }
}

// ---------------- folded bias fb[n] (fp32) ----------------
__global__ void prep_b_kernel(const float* __restrict__ bq, const float* __restrict__ bk,
                              const float* __restrict__ bv, const float* __restrict__ E,
                              const float* __restrict__ fw, float* __restrict__ fb){
  const int n = blockIdx.x * blockDim.x + threadIdx.x;
  if(n >= NQKV) return;
  const int p = n >> 10, kE = (n >> 6) & 15, d = n & 63;
  const float* b = (p == 0) ? bq : (p == 1) ? bk : bv;
  float acc = 0.f;
  for(int h = 0; h < 16; ++h) acc += E[h * 16 + kE] * b[h * 64 + d];
  fb[n] = acc * fw[kE];
}

// ---------------- 256x256 GEMM, K-tile-granular dbuf, ONE barrier per K-tile ----------------
// 512 thr = 8 waves (2M x 4N), BK=64, dbuf 2 x 64KB LDS (disjoint buffers).
// Within tile T: reads touch ONLY buf[T&1], stage-writes ONLY buf[(T+1)&1] -> no intra-tile
// barriers needed. Every wave's ds_reads are consumed by its own MFMAs (compiler auto-waitcnt)
// before the tile-end barrier, so one [vmcnt(0); s_barrier] per K-tile covers both hazards:
//   - read-ready: all 8 waves' stage loads for T+1 landed (own vmcnt) + barrier
//   - write-safety: all waves done reading buf[T] before anyone stages T+2 into it
// Flight time for T+1's loads = ~full tile (>2000cy >> ~900cy HBM) -> the vmcnt(0) is free.
// No manual lgkmcnt: compiler emits exact counted waits and can pipeline ds_read vs MFMA.
// LDS swizzle (both-sides XOR, rule #21): verified round 1 (bank conflicts 1.26e7 -> 0).
struct FlagF { static constexpr bool value = false; };
struct FlagT { static constexpr bool value = true; };

__global__ __launch_bounds__(512, 2)
void gemm_qkv_kernel(const _Float16* __restrict__ A,   // [16384][1024] fp16
                     const _Float16* __restrict__ BT,  // [3072][1024] fp16
                     const float* __restrict__ bias,   // [3072] fp32
                     _Float16* __restrict__ C){        // [16384][3072] fp16
  extern __shared__ _Float16 lds[];   // 65536 halfs = 128KB: buf[2] x {A 16384, B 16384}
  const int t = threadIdx.x;
  const int lane = t & 63, wv = t >> 6;
  const int l15 = lane & 15, q = lane >> 4;
  const int wr = wv >> 2, wc = wv & 3;           // 2M x 4N waves

  // T1: XCD band swizzle. 768 wgs, 96/XCD = 8 m-tiles x 12 n-tiles, m fast (B-tile L2-hot).
  const int bid = blockIdx.x;
  const int xcd = bid & 7, s = bid >> 3;         // s in 0..95
  const int mt = xcd * 8 + (s & 7);              // 0..63
  const int nt = s >> 3;                         // 0..11
  const int m0 = mt * 256, n0 = nt * 256;

  // staging lane constants (source pre-swizzle; dest linear)
  const int stR = wv * 16 + (lane >> 3);                 // row in half-tile
  const int stC = (((lane & 7) ^ (lane >> 3)) * 8);      // swizzled col (halfs)
  const int stD = (wv * 128 + lane) * 8;                 // dest (halfs, linear)
  // read-side swizzle: chunk col (halfs) = (q*8) ^ ((l15&7)*8), kk toggles ^32
  const int qsw = (q * 8) ^ ((l15 & 7) * 8);
  const int aoffb = (wr * 16 + l15) * 64;                // + m*2048 + (qsw ^ kk*32)
  const int boffb = (wc * 16 + l15) * 64;                // + n*4096 + (qsw ^ kk*32)

  auto stgA = [&](_Float16* nb, int kc, int h){
    const _Float16* g = A + (size_t)(m0 + h * 128 + stR) * 1024 + kc + stC;
    _Float16* d = nb + h * 8192 + stD;
    async_cp16(g, d);
    async_cp16(g + 8 * 1024, d + 512);
  };
  auto stgB = [&](_Float16* nb, int kc, int h){
    const _Float16* g = BT + (size_t)(n0 + h * 128 + stR) * 1024 + kc + stC;
    _Float16* d = nb + 16384 + h * 8192 + stD;
    async_cp16(g, d);
    async_cp16(g + 8 * 1024, d + 512);
  };

  float4v acc[8][4];
  #pragma unroll
  for(int m = 0; m < 8; ++m)
    #pragma unroll
    for(int n = 0; n < 4; ++n){ acc[m][n][0]=0.f; acc[m][n][1]=0.f; acc[m][n][2]=0.f; acc[m][n][3]=0.f; }

  half8 aL[4][2], aH[4][2], b0[2][2], b1[2][2];

  // prologue: stage K-tile 0, drain, sync
  stgA(lds, 0, 0);
  stgB(lds, 0, 0);
  stgB(lds, 0, 1);
  stgA(lds, 0, 1);
  VMCNT(0);
  BARX();

  int kt = 0;
  auto ktile = [&](auto lastc){
    constexpr bool LAST = decltype(lastc)::value;
    const _Float16* pA = lds + (kt & 1) * 32768;
    const _Float16* pB = pA + 16384;
    _Float16* nxt = lds + ((kt + 1) & 1) * 32768;
    const int kn = (kt + 1) * 64;

    // ---- quadrant (0,0): reads + stage issue, then MFMA ----
    #pragma unroll
    for(int m = 0; m < 4; ++m){
      aL[m][0] = *(const half8*)(pA + aoffb + m * 2048 + qsw);
      aL[m][1] = *(const half8*)(pA + aoffb + m * 2048 + (qsw ^ 32));
    }
    #pragma unroll
    for(int n = 0; n < 2; ++n){
      b0[n][0] = *(const half8*)(pB + boffb + n * 4096 + qsw);
      b0[n][1] = *(const half8*)(pB + boffb + n * 4096 + (qsw ^ 32));
    }
    if constexpr(!LAST) stgA(nxt, kn, 0);
    __builtin_amdgcn_s_setprio(1);
    #pragma unroll
    for(int m = 0; m < 4; ++m)
      #pragma unroll
      for(int n = 0; n < 2; ++n){
        acc[m][n] = MFMA16(aL[m][0], b0[n][0], acc[m][n], 0, 0, 0);
        acc[m][n] = MFMA16(aL[m][1], b0[n][1], acc[m][n], 0, 0, 0);
      }
    __builtin_amdgcn_s_setprio(0);

    // ---- quadrant (0,1) ----
    #pragma unroll
    for(int n = 0; n < 2; ++n){
      b1[n][0] = *(const half8*)(pB + boffb + (n + 2) * 4096 + qsw);
      b1[n][1] = *(const half8*)(pB + boffb + (n + 2) * 4096 + (qsw ^ 32));
    }
    if constexpr(!LAST) stgB(nxt, kn, 0);
    __builtin_amdgcn_s_setprio(1);
    #pragma unroll
    for(int m = 0; m < 4; ++m)
      #pragma unroll
      for(int n = 0; n < 2; ++n){
        acc[m][n + 2] = MFMA16(aL[m][0], b1[n][0], acc[m][n + 2], 0, 0, 0);
        acc[m][n + 2] = MFMA16(aL[m][1], b1[n][1], acc[m][n + 2], 0, 0, 0);
      }
    __builtin_amdgcn_s_setprio(0);

    // ---- quadrant (1,0) ----
    #pragma unroll
    for(int m = 0; m < 4; ++m){
      aH[m][0] = *(const half8*)(pA + aoffb + (m + 4) * 2048 + qsw);
      aH[m][1] = *(const half8*)(pA + aoffb + (m + 4) * 2048 + (qsw ^ 32));
    }
    if constexpr(!LAST) stgB(nxt, kn, 1);
    __builtin_amdgcn_s_setprio(1);
    #pragma unroll
    for(int m = 0; m < 4; ++m)
      #pragma unroll
      for(int n = 0; n < 2; ++n){
        acc[m + 4][n] = MFMA16(aH[m][0], b0[n][0], acc[m + 4][n], 0, 0, 0);
        acc[m + 4][n] = MFMA16(aH[m][1], b0[n][1], acc[m + 4][n], 0, 0, 0);
      }
    __builtin_amdgcn_s_setprio(0);

    // ---- quadrant (1,1), regs only ----
    if constexpr(!LAST) stgA(nxt, kn, 1);
    __builtin_amdgcn_s_setprio(1);
    #pragma unroll
    for(int m = 0; m < 4; ++m)
      #pragma unroll
      for(int n = 0; n < 2; ++n){
        acc[m + 4][n + 2] = MFMA16(aH[m][0], b1[n][0], acc[m + 4][n + 2], 0, 0, 0);
        acc[m + 4][n + 2] = MFMA16(aH[m][1], b1[n][1], acc[m + 4][n + 2], 0, 0, 0);
      }
    __builtin_amdgcn_s_setprio(0);

    // ---- tile boundary: single drain + barrier ----
    if constexpr(!LAST){
      VMCNT(0);        // T+1's 8 loads landed (flight ~ full tile, no stall expected)
      BARX();          // all waves done reading buf[T]; buf[T] free for T+2 staging
    }
  };

  for(kt = 0; kt < 15; ++kt) ktile(FlagF{});
  ktile(FlagT{});

  // epilogue: bias + fp16 store (same mapping as verified m97 kernel)
  #pragma unroll
  for(int n = 0; n < 4; ++n){
    const int col = n0 + (n * 4 + wc) * 16 + l15;
    const float bs = bias[col];
    #pragma unroll
    for(int m = 0; m < 8; ++m){
      const int rbase = m0 + (m * 2 + wr) * 16 + q * 4;
      #pragma unroll
      for(int r = 0; r < 4; ++r)
        C[(size_t)(rbase + r) * NQKV + col] = (_Float16)(acc[m][n][r] + bs);
    }
  }
}

// ---------------- per-token spectral attention v3 (unchanged) ----------------
__global__ __launch_bounds__(256)
void attn_kernel(const _Float16* __restrict__ QKV,   // [NTOK][3072] fp16
                 const float* __restrict__ E,        // [16][16] fp32
                 float* __restrict__ out){           // [NTOK][1024] fp32
  __shared__ _Float16 sV[4 * 1024];
  __shared__ _Float16 sE[16 * 32];
  __shared__ _Float16 pT[4][16 * 32];
  __shared__ _Float16 gT[4][16 * 32];

  const int t = threadIdx.x, lane = t & 63, wv = t >> 6;
  const int l15 = lane & 15, q = lane >> 4;

  {
    #pragma unroll
    for(int s = 0; s < 2; ++s){
      const int idx = s * 256 + t;
      const int row = idx >> 5, col = idx & 31;
      sE[idx] = (col < 16) ? (_Float16)E[row * 16 + col] : (_Float16)0.f;
    }
    #pragma unroll
    for(int s = 0; s < 4; ++s){
      const int idx = s * 256 + t;
      const int w = idx >> 8, rem = idx & 255;
      const int off = (rem >> 4) * 32 + 16 + (rem & 15);
      pT[w][off] = (_Float16)0.f;
      gT[w][off] = (_Float16)0.f;
    }
  }

  const _Float16* gb = QKV + (size_t)blockIdx.x * (4 * 3072);
  #pragma unroll
  for(int i = 0; i < 2; ++i){
    const int f = i * 256 + t;
    async_cp16(gb + (f >> 7) * 3072 + 2048 + (f & 127) * 8, sV + f * 8);
  }

  const int tok = blockIdx.x * 4 + wv;
  const _Float16* tg = QKV + (size_t)tok * 3072;

  half8 aK0 = *(const half8*)(tg + 1024 + l15 * 64 + q * 8);
  half8 aK1 = *(const half8*)(tg + 1024 + l15 * 64 + 32 + q * 8);
  half8 bQ0 = *(const half8*)(tg + l15 * 64 + q * 8);
  half8 bQ1 = *(const half8*)(tg + l15 * 64 + 32 + q * 8);
  float4v S; S[0]=0.f; S[1]=0.f; S[2]=0.f; S[3]=0.f;
  S = __builtin_amdgcn_mfma_f32_16x16x32_f16(aK0, bQ0, S, 0, 0, 0);
  S = __builtin_amdgcn_mfma_f32_16x16x32_f16(aK1, bQ1, S, 0, 0, 0);

  float v[4];
  #pragma unroll
  for(int r = 0; r < 4; ++r) v[r] = S[r] * 0.125f;
  float mx = fmaxf(fmaxf(v[0], v[1]), fmaxf(v[2], v[3]));
  mx = fmaxf(mx, __shfl_xor(mx, 16));
  mx = fmaxf(mx, __shfl_xor(mx, 32));
  float e[4];
  #pragma unroll
  for(int r = 0; r < 4; ++r) e[r] = __expf(v[r] - mx);
  float sm = (e[0] + e[1]) + (e[2] + e[3]);
  sm += __shfl_xor(sm, 16);
  sm += __shfl_xor(sm, 32);
  const float rs = 1.f / sm;

  __syncthreads();

  _Float16* pw = pT[wv];
  #pragma unroll
  for(int r = 0; r < 4; ++r) pw[(q * 4 + r) * 32 + l15] = (_Float16)(e[r] * rs);
  half8 bP = *(const half8*)(pw + l15 * 32 + q * 8);
  half8 aE = *(const half8*)(sE + l15 * 32 + q * 8);

  float4v G; G[0]=0.f; G[1]=0.f; G[2]=0.f; G[3]=0.f;
  G = __builtin_amdgcn_mfma_f32_16x16x32_f16(aE, bP, G, 0, 0, 0);

  _Float16* gw = gT[wv];
  #pragma unroll
  for(int r = 0; r < 4; ++r) gw[(q * 4 + r) * 32 + l15] = (_Float16)G[r];
  half8 aG = *(const half8*)(gw + l15 * 32 + q * 8);

  const _Float16* vb = sV + wv * 1024 + (q & 1) * 8 * 64;
  float* ob = out + (size_t)tok * 1024;
  #pragma unroll
  for(int tt = 0; tt < 4; ++tt){
    half8 vf;
    #pragma unroll
    for(int jj = 0; jj < 8; ++jj) vf[jj] = vb[jj * 64 + tt * 16 + l15];
    float4v O; O[0]=0.f; O[1]=0.f; O[2]=0.f; O[3]=0.f;
    O = __builtin_amdgcn_mfma_f32_16x16x32_f16(aG, vf, O, 0, 0, 0);
    #pragma unroll
    for(int r = 0; r < 4; ++r)
      ob[(q * 4 + r) * 64 + tt * 16 + l15] = O[r];
  }
}

extern "C" void kernel_launch(void* const* d_in, const int* in_sizes, int n_in,
                              void* d_out, int out_size, void* d_ws, size_t ws_size,
                              hipStream_t stream){
  const float* x  = (const float*)d_in[0];
  const float* Wq = (const float*)d_in[1];
  const float* bq = (const float*)d_in[2];
  const float* Wk = (const float*)d_in[3];
  const float* bk = (const float*)d_in[4];
  const float* Wv = (const float*)d_in[5];
  const float* bv = (const float*)d_in[6];
  const float* E  = (const float*)d_in[7];
  const float* fw = (const float*)d_in[8];
  float* out = (float*)d_out;

  // workspace layout (needs 136 MB)
  char* ws = (char*)d_ws;
  _Float16* xb  = (_Float16*)ws;                                  // 32 MB
  _Float16* WT  = (_Float16*)(ws + (size_t)32 * 1024 * 1024);     //  6 MB
  float*    fb  = (float*)   (ws + (size_t)39 * 1024 * 1024);     // 12 KB
  _Float16* QKV = (_Float16*)(ws + (size_t)40 * 1024 * 1024);     // 96 MB

  static bool attr_done = false;
  if(!attr_done){
    hipFuncSetAttribute((const void*)gemm_qkv_kernel,
                        hipFuncAttributeMaxDynamicSharedMemorySize, 131072);
    attr_done = true;
  }

  hipLaunchKernelGGL(cvt_x_kernel, dim3(2048), dim3(256), 0, stream, x, xb);
  hipLaunchKernelGGL(prep_w_kernel, dim3(384), dim3(256), 0, stream, Wq, Wk, Wv, E, fw, WT);
  hipLaunchKernelGGL(prep_b_kernel, dim3(12), dim3(256), 0, stream, bq, bk, bv, E, fw, fb);
  hipLaunchKernelGGL(gemm_qkv_kernel, dim3(768), dim3(512), 131072, stream, xb, WT, fb, QKV);
  hipLaunchKernelGGL(attn_kernel, dim3(NTOK / 4), dim3(256), 0, stream, QKV, E, out);
}